// Round 4
// baseline (261.657 us; speedup 1.0000x reference)
//
#include <hip/hip_runtime.h>
#include <cstdint>
#include <cstddef>

// Problem constants
#define BATCH 8
#define CDIM  512
#define NPIX  4096   // 64*64
#define NHEAD 8
#define DH    64
#define KTOK  64
#define MEM   512

#define BK    64     // GEMM K-step
#define TSTR  72     // LDS row stride in shorts (144B): 16B-aligned b128 reads, ~2-way banks

typedef __attribute__((ext_vector_type(8))) short          bf8;   // MFMA A/B operand (8 bf16)
typedef __attribute__((ext_vector_type(4))) float          f4;    // MFMA C/D
typedef __attribute__((ext_vector_type(4))) unsigned short us4;   // 8-byte bf16 pack

__device__ __forceinline__ unsigned short f2bf(float f){
  union { float f; unsigned int u; } x; x.f = f;
  unsigned int r = (x.u + 0x7fffu + ((x.u >> 16) & 1u)) >> 16;
  return (unsigned short)r;
}

// ---------------- K0: weights fp32 -> bf16 ----------------
__global__ __launch_bounds__(256) void wconv(const float* __restrict__ wq, const float* __restrict__ wp,
                                             unsigned short* __restrict__ wqb, unsigned short* __restrict__ wpb){
  int i = (blockIdx.x * 256 + threadIdx.x) * 4;   // grid 256 -> covers 262144
  float4 a = *(const float4*)(wq + i);
  us4 pa = { f2bf(a.x), f2bf(a.y), f2bf(a.z), f2bf(a.w) };
  *(us4*)(wqb + i) = pa;
  float4 b = *(const float4*)(wp + i);
  us4 pb = { f2bf(b.x), f2bf(b.y), f2bf(b.z), f2bf(b.w) };
  *(us4*)(wpb + i) = pb;
}

// ---------------- K0b: x [b][c][n] fp32 -> xb [b][n][c] bf16 ----------------
__global__ __launch_bounds__(256) void xtrans(const float* __restrict__ x, unsigned short* __restrict__ xb){
  __shared__ __align__(16) unsigned short t[64 * 68];
  int tid = threadIdx.x;
  int n0 = blockIdx.x * 64, c0 = blockIdx.y * 64, b = blockIdx.z;
  const float* xp = x + ((size_t)(b * CDIM + c0)) * NPIX + n0;
#pragma unroll
  for (int it = 0; it < 4; ++it){
    int idx = it * 1024 + tid * 4;
    int cc = idx >> 6, nn = idx & 63;
    float4 v = *(const float4*)(xp + (size_t)cc * NPIX + nn);
    us4 pk = { f2bf(v.x), f2bf(v.y), f2bf(v.z), f2bf(v.w) };
    *(us4*)&t[cc * 68 + nn] = pk;
  }
  __syncthreads();
  unsigned short* op = xb + ((size_t)(b * NPIX + n0)) * CDIM + c0;
#pragma unroll
  for (int it = 0; it < 4; ++it){
    int idx = it * 1024 + tid * 4;
    int nn = idx >> 6, c4 = idx & 63;
    us4 pk = { t[(c4 + 0) * 68 + nn], t[(c4 + 1) * 68 + nn],
               t[(c4 + 2) * 68 + nn], t[(c4 + 3) * 68 + nn] };
    *(us4*)(op + (size_t)nn * CDIM + c4) = pk;
  }
}

// ---------------- K1: K/V projection (fp32 compute, bf16 out) ----------------
__global__ __launch_bounds__(256) void kvproj(const float* __restrict__ Ft, const float* __restrict__ Wk,
                                              const float* __restrict__ Wv, unsigned short* __restrict__ kb,
                                              unsigned short* __restrict__ vt){
  __shared__ float ft[8][MEM];
  int tid = threadIdx.x;
  int cg = blockIdx.x, kk0 = blockIdx.y * 8, b = blockIdx.z;
  const float* fp = Ft + ((size_t)(b * KTOK + kk0)) * MEM;
#pragma unroll
  for (int it = 0; it < 4; ++it){
    int idx = it * 1024 + tid * 4;
    int row = idx >> 9, m = idx & 511;
    *(float4*)&ft[row][m] = *(const float4*)(fp + (size_t)row * MEM + m);
  }
  __syncthreads();
  int kv = tid >> 7, cl = tid & 127;
  int c = cg * 128 + cl;
  const float* wrow = (kv ? Wv : Wk) + (size_t)c * MEM;
  float acc[8] = {0.f,0.f,0.f,0.f,0.f,0.f,0.f,0.f};
  for (int m = 0; m < MEM; m += 4){
    float4 wv4 = *(const float4*)(wrow + m);
#pragma unroll
    for (int kk = 0; kk < 8; ++kk){
      acc[kk] += wv4.x * ft[kk][m] + wv4.y * ft[kk][m+1] + wv4.z * ft[kk][m+2] + wv4.w * ft[kk][m+3];
    }
  }
  int h = c >> 6, dd = c & 63;
  if (kv == 0){
#pragma unroll
    for (int kk = 0; kk < 8; ++kk)
      kb[(((size_t)(b * NHEAD + h)) * KTOK + kk0 + kk) * DH + dd] = f2bf(acc[kk] * 0.125f);
  } else {
#pragma unroll
    for (int kk = 0; kk < 8; ++kk)
      vt[(((size_t)(b * NHEAD + h)) * DH + dd) * KTOK + kk0 + kk] = f2bf(acc[kk]);
  }
}

// ---------------- K2: fused q-projection + attention ----------------
// Block: 128 o x 128 n tile; 4 waves (2x2 of 64x64). Wave's 64 o-rows = one head.
// LDS (36.9KB): staging A[128][TSTR] + B[128][TSTR] aliased with per-wave qt/P regions.
__global__ __launch_bounds__(256, 4) void qattn(const unsigned short* __restrict__ wqb,
                                                const unsigned short* __restrict__ xb,
                                                const unsigned short* __restrict__ kb,
                                                const unsigned short* __restrict__ vt,
                                                unsigned short* __restrict__ att){
  __shared__ __align__(16) unsigned short ab[18432];   // 36,864 B
  int tid = threadIdx.x;
  int w = tid >> 6, l = tid & 63;
  int lo = l & 15, hi = l >> 4;
  int n0 = blockIdx.x * 128, o0 = blockIdx.y * 128, b = blockIdx.z;
  int ol = (w >> 1) * 64, nl = (w & 1) * 64;

  f4 z = {0.f, 0.f, 0.f, 0.f};
  f4 accq[4][4];
#pragma unroll
  for (int i = 0; i < 4; ++i)
#pragma unroll
    for (int j = 0; j < 4; ++j) accq[i][j] = z;

  // staging map: thread -> (row sr + i*32, cols sc..sc+7), 8x16B per thread per K-step
  const int sr = tid >> 3;          // 0..31
  const int sc = (tid & 7) * 8;     // 0..56
  const unsigned short* ap = wqb + ((size_t)(o0 + sr)) * CDIM + sc;
  const unsigned short* bp = xb + ((size_t)(b * NPIX + n0 + sr)) * CDIM + sc;
  unsigned short* as = &ab[sr * TSTR + sc];
  unsigned short* bs = &ab[9216 + sr * TSTR + sc];

  uint4 ra[4], rb[4];
#pragma unroll
  for (int i = 0; i < 4; ++i){
    ra[i] = *(const uint4*)(ap + (size_t)i * 32 * CDIM);
    rb[i] = *(const uint4*)(bp + (size_t)i * 32 * CDIM);
  }

  for (int t = 0; t < 8; ++t){
    __syncthreads();                       // WAR: previous iter's fragment reads done
#pragma unroll
    for (int i = 0; i < 4; ++i){
      *(uint4*)(as + i * 32 * TSTR) = ra[i];
      *(uint4*)(bs + i * 32 * TSTR) = rb[i];
    }
    __syncthreads();
    if (t < 7){
      int kc = (t + 1) * BK;
#pragma unroll
      for (int i = 0; i < 4; ++i){
        ra[i] = *(const uint4*)(ap + (size_t)i * 32 * CDIM + kc);
        rb[i] = *(const uint4*)(bp + (size_t)i * 32 * CDIM + kc);
      }
    }
#pragma unroll
    for (int ks = 0; ks < 2; ++ks){
      bf8 af[4], bfr[4];
#pragma unroll
      for (int fi = 0; fi < 4; ++fi)
        af[fi] = *(const bf8*)&ab[(ol + fi * 16 + lo) * TSTR + ks * 32 + hi * 8];
#pragma unroll
      for (int fj = 0; fj < 4; ++fj)
        bfr[fj] = *(const bf8*)&ab[9216 + (nl + fj * 16 + lo) * TSTR + ks * 32 + hi * 8];
#pragma unroll
      for (int fi = 0; fi < 4; ++fi)
#pragma unroll
        for (int fj = 0; fj < 4; ++fj)
          accq[fi][fj] = __builtin_amdgcn_mfma_f32_16x16x32_bf16(af[fi], bfr[fj], accq[fi][fj], 0, 0, 0);
    }
  }
  __syncthreads();   // all staging reads done before qt overwrite (qt aliases staging tiles)

  // Write q (bf16) to per-wave LDS as qt[n][dd]. D-layout: row(o/dd)=fi*16+hi*4+r, col(n)=fj*16+lo.
  unsigned short* qt = &ab[w * 4608];
#pragma unroll
  for (int fi = 0; fi < 4; ++fi)
#pragma unroll
    for (int fj = 0; fj < 4; ++fj){
      f4 v = accq[fi][fj];
      us4 pk = { f2bf(v[0]), f2bf(v[1]), f2bf(v[2]), f2bf(v[3]) };
      *(us4*)&qt[(fj * 16 + lo) * TSTR + fi * 16 + hi * 4] = pk;
    }

  int head = blockIdx.y * 2 + (w >> 1);
  // S^T[kk][n] = sum_dd k[kk][dd] * q[n][dd] ; k pre-scaled by 1/sqrt(d)
  const unsigned short* kh = kb + ((size_t)(b * NHEAD + head)) * (KTOK * DH);
  f4 accs[4][4];
#pragma unroll
  for (int i = 0; i < 4; ++i)
#pragma unroll
    for (int j = 0; j < 4; ++j) accs[i][j] = z;
#pragma unroll
  for (int ks = 0; ks < 2; ++ks){
    bf8 ka[4];
#pragma unroll
    for (int fi = 0; fi < 4; ++fi)
      ka[fi] = *(const bf8*)(kh + (fi * 16 + lo) * 64 + ks * 32 + hi * 8);
#pragma unroll
    for (int fj = 0; fj < 4; ++fj){
      bf8 qf = *(const bf8*)&qt[(fj * 16 + lo) * TSTR + ks * 32 + hi * 8];
#pragma unroll
      for (int fi = 0; fi < 4; ++fi)
        accs[fi][fj] = __builtin_amdgcn_mfma_f32_16x16x32_bf16(ka[fi], qf, accs[fi][fj], 0, 0, 0);
    }
  }

  // Softmax over kk (per n-column): 16 local values (fi x r) + shuffles across l^16, l^32.
  // P overwrites the wave's own qt region (wave-local WAR; lgkmcnt order preserves it).
#pragma unroll
  for (int fj = 0; fj < 4; ++fj){
    float mx = accs[0][fj][0];
#pragma unroll
    for (int fi = 0; fi < 4; ++fi)
#pragma unroll
      for (int r = 0; r < 4; ++r) mx = fmaxf(mx, accs[fi][fj][r]);
    mx = fmaxf(mx, __shfl_xor(mx, 16));
    mx = fmaxf(mx, __shfl_xor(mx, 32));
    float sm = 0.f;
#pragma unroll
    for (int fi = 0; fi < 4; ++fi)
#pragma unroll
      for (int r = 0; r < 4; ++r){
        float e = __expf(accs[fi][fj][r] - mx);
        accs[fi][fj][r] = e; sm += e;
      }
    sm += __shfl_xor(sm, 16);
    sm += __shfl_xor(sm, 32);
    float inv = 1.0f / sm;
#pragma unroll
    for (int fi = 0; fi < 4; ++fi){
      us4 pk = { f2bf(accs[fi][fj][0] * inv), f2bf(accs[fi][fj][1] * inv),
                 f2bf(accs[fi][fj][2] * inv), f2bf(accs[fi][fj][3] * inv) };
      *(us4*)&qt[(fj * 16 + lo) * TSTR + fi * 16 + hi * 4] = pk;
    }
  }

  // out^T[dd][n] = sum_kk vt[dd][kk] * P[n][kk]
  const unsigned short* vh = vt + ((size_t)(b * NHEAD + head)) * (DH * KTOK);
  f4 acco[4][4];
#pragma unroll
  for (int i = 0; i < 4; ++i)
#pragma unroll
    for (int j = 0; j < 4; ++j) acco[i][j] = z;
#pragma unroll
  for (int ks = 0; ks < 2; ++ks){
    bf8 va[4];
#pragma unroll
    for (int fi = 0; fi < 4; ++fi)
      va[fi] = *(const bf8*)(vh + (fi * 16 + lo) * 64 + ks * 32 + hi * 8);
#pragma unroll
    for (int fj = 0; fj < 4; ++fj){
      bf8 pf = *(const bf8*)&qt[(fj * 16 + lo) * TSTR + ks * 32 + hi * 8];
#pragma unroll
      for (int fi = 0; fi < 4; ++fi)
        acco[fi][fj] = __builtin_amdgcn_mfma_f32_16x16x32_bf16(va[fi], pf, acco[fi][fj], 0, 0, 0);
    }
  }

  // Write att[b][n][c] bf16; c = head*64 + dd, dd = fi*16 + hi*4 + r
  unsigned short* op = att + ((size_t)(b * NPIX + n0 + nl)) * CDIM + head * 64;
#pragma unroll
  for (int fi = 0; fi < 4; ++fi)
#pragma unroll
    for (int fj = 0; fj < 4; ++fj){
      f4 v = acco[fi][fj];
      us4 pk = { f2bf(v[0]), f2bf(v[1]), f2bf(v[2]), f2bf(v[3]) };
      *(us4*)(op + (size_t)(fj * 16 + lo) * CDIM + fi * 16 + hi * 4) = pk;
    }
}

// ---------------- K3: output projection + bias + residual ----------------
__global__ __launch_bounds__(256, 4) void pproj(const unsigned short* __restrict__ wpb,
                                                const unsigned short* __restrict__ att,
                                                const float* __restrict__ x,
                                                const float* __restrict__ bpv,
                                                float* __restrict__ out){
  __shared__ __align__(16) unsigned short ab[18432];   // 36,864 B
  int tid = threadIdx.x;
  int w = tid >> 6, l = tid & 63;
  int lo = l & 15, hi = l >> 4;
  int n0 = blockIdx.x * 128, o0 = blockIdx.y * 128, b = blockIdx.z;
  int ol = (w >> 1) * 64, nl = (w & 1) * 64;

  f4 z = {0.f, 0.f, 0.f, 0.f};
  f4 acc[4][4];
#pragma unroll
  for (int i = 0; i < 4; ++i)
#pragma unroll
    for (int j = 0; j < 4; ++j) acc[i][j] = z;

  const int sr = tid >> 3;
  const int sc = (tid & 7) * 8;
  const unsigned short* ap = wpb + ((size_t)(o0 + sr)) * CDIM + sc;
  const unsigned short* bp = att + ((size_t)(b * NPIX + n0 + sr)) * CDIM + sc;
  unsigned short* as = &ab[sr * TSTR + sc];
  unsigned short* bs = &ab[9216 + sr * TSTR + sc];

  uint4 ra[4], rb[4];
#pragma unroll
  for (int i = 0; i < 4; ++i){
    ra[i] = *(const uint4*)(ap + (size_t)i * 32 * CDIM);
    rb[i] = *(const uint4*)(bp + (size_t)i * 32 * CDIM);
  }

  for (int t = 0; t < 8; ++t){
    __syncthreads();
#pragma unroll
    for (int i = 0; i < 4; ++i){
      *(uint4*)(as + i * 32 * TSTR) = ra[i];
      *(uint4*)(bs + i * 32 * TSTR) = rb[i];
    }
    __syncthreads();
    if (t < 7){
      int kc = (t + 1) * BK;
#pragma unroll
      for (int i = 0; i < 4; ++i){
        ra[i] = *(const uint4*)(ap + (size_t)i * 32 * CDIM + kc);
        rb[i] = *(const uint4*)(bp + (size_t)i * 32 * CDIM + kc);
      }
    }
#pragma unroll
    for (int ks = 0; ks < 2; ++ks){
      bf8 af[4], bfr[4];
#pragma unroll
      for (int fi = 0; fi < 4; ++fi)
        af[fi] = *(const bf8*)&ab[(ol + fi * 16 + lo) * TSTR + ks * 32 + hi * 8];
#pragma unroll
      for (int fj = 0; fj < 4; ++fj)
        bfr[fj] = *(const bf8*)&ab[9216 + (nl + fj * 16 + lo) * TSTR + ks * 32 + hi * 8];
#pragma unroll
      for (int fi = 0; fi < 4; ++fi)
#pragma unroll
        for (int fj = 0; fj < 4; ++fj)
          acc[fi][fj] = __builtin_amdgcn_mfma_f32_16x16x32_bf16(af[fi], bfr[fj], acc[fi][fj], 0, 0, 0);
    }
  }

#pragma unroll
  for (int fi = 0; fi < 4; ++fi)
#pragma unroll
    for (int fj = 0; fj < 4; ++fj){
      int o = o0 + ol + fi * 16 + hi * 4;
      int n = n0 + nl + fj * 16 + lo;
#pragma unroll
      for (int r = 0; r < 4; ++r){
        size_t idx = ((size_t)(b * CDIM + o + r)) * NPIX + n;
        out[idx] = acc[fi][fj][r] + bpv[o + r] + x[idx];
      }
    }
}

extern "C" void kernel_launch(void* const* d_in, const int* in_sizes, int n_in,
                              void* d_out, int out_size, void* d_ws, size_t ws_size,
                              hipStream_t stream){
  const float* x  = (const float*)d_in[0];
  const float* Ft = (const float*)d_in[1];
  const float* Wq = (const float*)d_in[2];
  const float* Wk = (const float*)d_in[3];
  const float* Wv = (const float*)d_in[4];
  const float* Wp = (const float*)d_in[5];
  const float* bp = (const float*)d_in[6];
  float* out = (float*)d_out;

  char* ws = (char*)d_ws;
  // ws layout (bytes): wqb 512K | wpb 512K | xb 32M | att 32M | kb 512K | vt 512K  (~66MB total)
  unsigned short* wqb = (unsigned short*)(ws);
  unsigned short* wpb = (unsigned short*)(ws + 524288);
  unsigned short* xb  = (unsigned short*)(ws + 1048576);
  unsigned short* att = (unsigned short*)(ws + 1048576 + 33554432);
  unsigned short* kb  = (unsigned short*)(ws + 1048576 + 2ull * 33554432);
  unsigned short* vt  = (unsigned short*)(ws + 1048576 + 2ull * 33554432 + 524288);

  wconv<<<dim3(256), dim3(256), 0, stream>>>(Wq, Wp, wqb, wpb);
  xtrans<<<dim3(64, 8, 8), dim3(256), 0, stream>>>(x, xb);
  kvproj<<<dim3(4, 8, 8), dim3(256), 0, stream>>>(Ft, Wk, Wv, kb, vt);
  qattn<<<dim3(32, 4, 8), dim3(256), 0, stream>>>(wqb, xb, kb, vt, att);
  pproj<<<dim3(32, 4, 8), dim3(256), 0, stream>>>(wpb, att, x, bp, out);
}

// Round 5
// 115.741 us; speedup vs baseline: 2.2607x; 2.2607x over previous
//
#include <hip/hip_runtime.h>
#include <cstdint>
#include <cstddef>

// Problem constants
#define BATCH 8
#define CDIM  512
#define NPIX  4096   // 64*64
#define NHEAD 8
#define DH    64
#define KTOK  64
#define MEM   512

#define BK    64     // GEMM K-step

typedef __attribute__((ext_vector_type(8))) short          bf8;   // MFMA A/B operand (8 bf16)
typedef __attribute__((ext_vector_type(4))) float          f4;    // MFMA C/D
typedef __attribute__((ext_vector_type(4))) unsigned short us4;   // 8-byte bf16 pack

__device__ __forceinline__ unsigned short f2bf(float f){
  union { float f; unsigned int u; } x; x.f = f;
  unsigned int r = (x.u + 0x7fffu + ((x.u >> 16) & 1u)) >> 16;
  return (unsigned short)r;
}

// async global->LDS DMA, 16B per lane; LDS dest = wave-uniform base + lane*16
__device__ __forceinline__ void gld_lds16(const unsigned short* g, unsigned short* lds){
  __builtin_amdgcn_global_load_lds((const __attribute__((address_space(1))) unsigned int*)g,
                                   (__attribute__((address_space(3))) unsigned int*)lds, 16, 0, 0);
}

// ---------------- K0: weights fp32 -> bf16 ----------------
__global__ __launch_bounds__(256) void wconv(const float* __restrict__ wq, const float* __restrict__ wp,
                                             unsigned short* __restrict__ wqb, unsigned short* __restrict__ wpb){
  int i = (blockIdx.x * 256 + threadIdx.x) * 4;   // grid 256 -> covers 262144
  float4 a = *(const float4*)(wq + i);
  us4 pa = { f2bf(a.x), f2bf(a.y), f2bf(a.z), f2bf(a.w) };
  *(us4*)(wqb + i) = pa;
  float4 b = *(const float4*)(wp + i);
  us4 pb = { f2bf(b.x), f2bf(b.y), f2bf(b.z), f2bf(b.w) };
  *(us4*)(wpb + i) = pb;
}

// ---------------- K0b: x [b][c][n] fp32 -> xb [b][n][c] bf16 ----------------
__global__ __launch_bounds__(256) void xtrans(const float* __restrict__ x, unsigned short* __restrict__ xb){
  __shared__ __align__(16) unsigned short t[64 * 68];
  int tid = threadIdx.x;
  int n0 = blockIdx.x * 64, c0 = blockIdx.y * 64, b = blockIdx.z;
  const float* xp = x + ((size_t)(b * CDIM + c0)) * NPIX + n0;
#pragma unroll
  for (int it = 0; it < 4; ++it){
    int idx = it * 1024 + tid * 4;
    int cc = idx >> 6, nn = idx & 63;
    float4 v = *(const float4*)(xp + (size_t)cc * NPIX + nn);
    us4 pk = { f2bf(v.x), f2bf(v.y), f2bf(v.z), f2bf(v.w) };
    *(us4*)&t[cc * 68 + nn] = pk;
  }
  __syncthreads();
  unsigned short* op = xb + ((size_t)(b * NPIX + n0)) * CDIM + c0;
#pragma unroll
  for (int it = 0; it < 4; ++it){
    int idx = it * 1024 + tid * 4;
    int nn = idx >> 6, c4 = idx & 63;
    us4 pk = { t[(c4 + 0) * 68 + nn], t[(c4 + 1) * 68 + nn],
               t[(c4 + 2) * 68 + nn], t[(c4 + 3) * 68 + nn] };
    *(us4*)(op + (size_t)nn * CDIM + c4) = pk;
  }
}

// ---------------- K1: K/V projection (fp32 compute, bf16 out) ----------------
__global__ __launch_bounds__(256) void kvproj(const float* __restrict__ Ft, const float* __restrict__ Wk,
                                              const float* __restrict__ Wv, unsigned short* __restrict__ kb,
                                              unsigned short* __restrict__ vt){
  __shared__ float ft[8][MEM];
  int tid = threadIdx.x;
  int cg = blockIdx.x, kk0 = blockIdx.y * 8, b = blockIdx.z;
  const float* fp = Ft + ((size_t)(b * KTOK + kk0)) * MEM;
#pragma unroll
  for (int it = 0; it < 4; ++it){
    int idx = it * 1024 + tid * 4;
    int row = idx >> 9, m = idx & 511;
    *(float4*)&ft[row][m] = *(const float4*)(fp + (size_t)row * MEM + m);
  }
  __syncthreads();
  int kv = tid >> 7, cl = tid & 127;
  int c = cg * 128 + cl;
  const float* wrow = (kv ? Wv : Wk) + (size_t)c * MEM;
  float acc[8] = {0.f,0.f,0.f,0.f,0.f,0.f,0.f,0.f};
  for (int m = 0; m < MEM; m += 4){
    float4 wv4 = *(const float4*)(wrow + m);
#pragma unroll
    for (int kk = 0; kk < 8; ++kk){
      acc[kk] += wv4.x * ft[kk][m] + wv4.y * ft[kk][m+1] + wv4.z * ft[kk][m+2] + wv4.w * ft[kk][m+3];
    }
  }
  int h = c >> 6, dd = c & 63;
  if (kv == 0){
#pragma unroll
    for (int kk = 0; kk < 8; ++kk)
      kb[(((size_t)(b * NHEAD + h)) * KTOK + kk0 + kk) * DH + dd] = f2bf(acc[kk] * 0.125f);
  } else {
#pragma unroll
    for (int kk = 0; kk < 8; ++kk)
      vt[(((size_t)(b * NHEAD + h)) * DH + dd) * KTOK + kk0 + kk] = f2bf(acc[kk]);
  }
}

// ---------------- K2: fused q-projection + attention ----------------
// 128x128 tile, 4 waves (2x2 of 64x64). A/B tiles [128][64] bf16, UNPADDED (global_load_lds),
// XOR-swizzled at 16B-chunk granularity: physical chunk = logical chunk ^ (row&7).
// Per-wave 64x64 qt/P tile (same swizzle) aliases the staging region after the GEMM loop.
__global__ __launch_bounds__(256, 3) void qattn(const unsigned short* __restrict__ wqb,
                                                const unsigned short* __restrict__ xb,
                                                const unsigned short* __restrict__ kb,
                                                const unsigned short* __restrict__ vt,
                                                unsigned short* __restrict__ att){
  __shared__ __align__(16) unsigned short ab[16384];   // 32 KB: A [0,8192), B [8192,16384)
  int tid = threadIdx.x;
  int w = tid >> 6, l = tid & 63;
  int lo = l & 15, hi = l >> 4;
  int n0 = blockIdx.x * 128, o0 = blockIdx.y * 128, b = blockIdx.z;
  int ol = (w >> 1) * 64, nl = (w & 1) * 64;

  f4 z = {0.f, 0.f, 0.f, 0.f};
  f4 accq[4][4];
#pragma unroll
  for (int i = 0; i < 4; ++i)
#pragma unroll
    for (int j = 0; j < 4; ++j) accq[i][j] = z;

  // staging source: lane l covers row (l>>3) of its 8-row group, pre-swizzled chunk (l&7)^(l>>3)
  const int lrow = l >> 3;
  const int lcc  = (l & 7) ^ lrow;
  const unsigned short* asrc = wqb + ((size_t)(o0 + w * 8 + lrow)) * CDIM + lcc * 8;
  const unsigned short* bsrc = xb + ((size_t)(b * NPIX + n0 + w * 8 + lrow)) * CDIM + lcc * 8;

  for (int t = 0; t < 8; ++t){
    int kc = t * BK;
#pragma unroll
    for (int j = 0; j < 4; ++j){
      int g = j * 4 + w;                       // 8-row group 0..15
      gld_lds16(asrc + (size_t)j * 32 * CDIM + kc, &ab[g * 512]);
      gld_lds16(bsrc + (size_t)j * 32 * CDIM + kc, &ab[8192 + g * 512]);
    }
    __syncthreads();                           // drain DMA (vmcnt0 per wave) + all waves ready
#pragma unroll
    for (int ks = 0; ks < 2; ++ks){
      int cc = ks * 4 + hi;                    // logical 16B chunk in row (0..7)
      int sw = ((cc ^ (lo & 7)) << 3);         // swizzled short-offset
      bf8 af[4], bfr[4];
#pragma unroll
      for (int fi = 0; fi < 4; ++fi)
        af[fi] = *(const bf8*)&ab[(ol + fi * 16 + lo) * 64 + sw];
#pragma unroll
      for (int fj = 0; fj < 4; ++fj)
        bfr[fj] = *(const bf8*)&ab[8192 + (nl + fj * 16 + lo) * 64 + sw];
#pragma unroll
      for (int fi = 0; fi < 4; ++fi)
#pragma unroll
        for (int fj = 0; fj < 4; ++fj)
          accq[fi][fj] = __builtin_amdgcn_mfma_f32_16x16x32_bf16(af[fi], bfr[fj], accq[fi][fj], 0, 0, 0);
    }
    __syncthreads();                           // WAR: reads done before next stage overwrites
  }

  // qt[n][dd] per-wave 64x64 swizzled tile, aliases staging (all reads drained by final barrier).
  // D-layout: row(o/dd)=fi*16+hi*4+r, col(n)=fj*16+lo.
  unsigned short* qt = &ab[w * 4096];
#pragma unroll
  for (int fi = 0; fi < 4; ++fi)
#pragma unroll
    for (int fj = 0; fj < 4; ++fj){
      f4 v = accq[fi][fj];
      us4 pk = { f2bf(v[0]), f2bf(v[1]), f2bf(v[2]), f2bf(v[3]) };
      int row = fj * 16 + lo;                  // n
      int col = fi * 16 + hi * 4;              // dd
      int cs  = (((col >> 3) ^ (row & 7)) << 3) | (col & 7);
      *(us4*)&qt[row * 64 + cs] = pk;
    }

  int head = blockIdx.y * 2 + (w >> 1);
  // S^T[kk][n] = sum_dd k[kk][dd] * q[n][dd] ; k pre-scaled by 1/sqrt(d)
  const unsigned short* kh = kb + ((size_t)(b * NHEAD + head)) * (KTOK * DH);
  f4 accs[4][4];
#pragma unroll
  for (int i = 0; i < 4; ++i)
#pragma unroll
    for (int j = 0; j < 4; ++j) accs[i][j] = z;
#pragma unroll
  for (int ks = 0; ks < 2; ++ks){
    int sw = (((ks * 4 + hi) ^ (lo & 7)) << 3);
    bf8 ka[4];
#pragma unroll
    for (int fi = 0; fi < 4; ++fi)
      ka[fi] = *(const bf8*)(kh + (fi * 16 + lo) * 64 + ks * 32 + hi * 8);
#pragma unroll
    for (int fj = 0; fj < 4; ++fj){
      bf8 qf = *(const bf8*)&qt[(fj * 16 + lo) * 64 + sw];
#pragma unroll
      for (int fi = 0; fi < 4; ++fi)
        accs[fi][fj] = __builtin_amdgcn_mfma_f32_16x16x32_bf16(ka[fi], qf, accs[fi][fj], 0, 0, 0);
    }
  }

  // Softmax over kk (per n-column): 16 local values (fi x r) + shuffles across l^16, l^32.
  // P overwrites the wave's own qt tile (wave-local WAR; LDS op order per wave preserves it).
#pragma unroll
  for (int fj = 0; fj < 4; ++fj){
    float mx = accs[0][fj][0];
#pragma unroll
    for (int fi = 0; fi < 4; ++fi)
#pragma unroll
      for (int r = 0; r < 4; ++r) mx = fmaxf(mx, accs[fi][fj][r]);
    mx = fmaxf(mx, __shfl_xor(mx, 16));
    mx = fmaxf(mx, __shfl_xor(mx, 32));
    float sm = 0.f;
#pragma unroll
    for (int fi = 0; fi < 4; ++fi)
#pragma unroll
      for (int r = 0; r < 4; ++r){
        float e = __expf(accs[fi][fj][r] - mx);
        accs[fi][fj][r] = e; sm += e;
      }
    sm += __shfl_xor(sm, 16);
    sm += __shfl_xor(sm, 32);
    float inv = 1.0f / sm;
#pragma unroll
    for (int fi = 0; fi < 4; ++fi){
      us4 pk = { f2bf(accs[fi][fj][0] * inv), f2bf(accs[fi][fj][1] * inv),
                 f2bf(accs[fi][fj][2] * inv), f2bf(accs[fi][fj][3] * inv) };
      int row = fj * 16 + lo;
      int col = fi * 16 + hi * 4;
      int cs  = (((col >> 3) ^ (row & 7)) << 3) | (col & 7);
      *(us4*)&qt[row * 64 + cs] = pk;
    }
  }

  // out^T[dd][n] = sum_kk vt[dd][kk] * P[n][kk]
  const unsigned short* vh = vt + ((size_t)(b * NHEAD + head)) * (DH * KTOK);
  f4 acco[4][4];
#pragma unroll
  for (int i = 0; i < 4; ++i)
#pragma unroll
    for (int j = 0; j < 4; ++j) acco[i][j] = z;
#pragma unroll
  for (int ks = 0; ks < 2; ++ks){
    int sw = (((ks * 4 + hi) ^ (lo & 7)) << 3);
    bf8 va[4];
#pragma unroll
    for (int fi = 0; fi < 4; ++fi)
      va[fi] = *(const bf8*)(vh + (fi * 16 + lo) * 64 + ks * 32 + hi * 8);
#pragma unroll
    for (int fj = 0; fj < 4; ++fj){
      bf8 pf = *(const bf8*)&qt[(fj * 16 + lo) * 64 + sw];
#pragma unroll
      for (int fi = 0; fi < 4; ++fi)
        acco[fi][fj] = __builtin_amdgcn_mfma_f32_16x16x32_bf16(va[fi], pf, acco[fi][fj], 0, 0, 0);
    }
  }

  // Write att[b][n][c] bf16; c = head*64 + dd, dd = fi*16 + hi*4 + r
  unsigned short* op = att + ((size_t)(b * NPIX + n0 + nl)) * CDIM + head * 64;
#pragma unroll
  for (int fi = 0; fi < 4; ++fi)
#pragma unroll
    for (int fj = 0; fj < 4; ++fj){
      f4 v = acco[fi][fj];
      us4 pk = { f2bf(v[0]), f2bf(v[1]), f2bf(v[2]), f2bf(v[3]) };
      *(us4*)(op + (size_t)(fj * 16 + lo) * CDIM + fi * 16 + hi * 4) = pk;
    }
}

// ---------------- K3: output projection + bias + residual ----------------
__global__ __launch_bounds__(256, 3) void pproj(const unsigned short* __restrict__ wpb,
                                                const unsigned short* __restrict__ att,
                                                const float* __restrict__ x,
                                                const float* __restrict__ bpv,
                                                float* __restrict__ out){
  __shared__ __align__(16) unsigned short ab[16384];   // 32 KB
  int tid = threadIdx.x;
  int w = tid >> 6, l = tid & 63;
  int lo = l & 15, hi = l >> 4;
  int n0 = blockIdx.x * 128, o0 = blockIdx.y * 128, b = blockIdx.z;
  int ol = (w >> 1) * 64, nl = (w & 1) * 64;

  f4 z = {0.f, 0.f, 0.f, 0.f};
  f4 acc[4][4];
#pragma unroll
  for (int i = 0; i < 4; ++i)
#pragma unroll
    for (int j = 0; j < 4; ++j) acc[i][j] = z;

  const int lrow = l >> 3;
  const int lcc  = (l & 7) ^ lrow;
  const unsigned short* asrc = wpb + ((size_t)(o0 + w * 8 + lrow)) * CDIM + lcc * 8;
  const unsigned short* bsrc = att + ((size_t)(b * NPIX + n0 + w * 8 + lrow)) * CDIM + lcc * 8;

  for (int t = 0; t < 8; ++t){
    int kc = t * BK;
#pragma unroll
    for (int j = 0; j < 4; ++j){
      int g = j * 4 + w;
      gld_lds16(asrc + (size_t)j * 32 * CDIM + kc, &ab[g * 512]);
      gld_lds16(bsrc + (size_t)j * 32 * CDIM + kc, &ab[8192 + g * 512]);
    }
    __syncthreads();
#pragma unroll
    for (int ks = 0; ks < 2; ++ks){
      int cc = ks * 4 + hi;
      int sw = ((cc ^ (lo & 7)) << 3);
      bf8 af[4], bfr[4];
#pragma unroll
      for (int fi = 0; fi < 4; ++fi)
        af[fi] = *(const bf8*)&ab[(ol + fi * 16 + lo) * 64 + sw];
#pragma unroll
      for (int fj = 0; fj < 4; ++fj)
        bfr[fj] = *(const bf8*)&ab[8192 + (nl + fj * 16 + lo) * 64 + sw];
#pragma unroll
      for (int fi = 0; fi < 4; ++fi)
#pragma unroll
        for (int fj = 0; fj < 4; ++fj)
          acc[fi][fj] = __builtin_amdgcn_mfma_f32_16x16x32_bf16(af[fi], bfr[fj], acc[fi][fj], 0, 0, 0);
    }
    __syncthreads();
  }

#pragma unroll
  for (int fi = 0; fi < 4; ++fi)
#pragma unroll
    for (int fj = 0; fj < 4; ++fj){
      int o = o0 + ol + fi * 16 + hi * 4;
      int n = n0 + nl + fj * 16 + lo;
#pragma unroll
      for (int r = 0; r < 4; ++r){
        size_t idx = ((size_t)(b * CDIM + o + r)) * NPIX + n;
        out[idx] = acc[fi][fj][r] + bpv[o + r] + x[idx];
      }
    }
}

extern "C" void kernel_launch(void* const* d_in, const int* in_sizes, int n_in,
                              void* d_out, int out_size, void* d_ws, size_t ws_size,
                              hipStream_t stream){
  const float* x  = (const float*)d_in[0];
  const float* Ft = (const float*)d_in[1];
  const float* Wq = (const float*)d_in[2];
  const float* Wk = (const float*)d_in[3];
  const float* Wv = (const float*)d_in[4];
  const float* Wp = (const float*)d_in[5];
  const float* bp = (const float*)d_in[6];
  float* out = (float*)d_out;

  char* ws = (char*)d_ws;
  // ws layout (bytes): wqb 512K | wpb 512K | xb 32M | att 32M | kb 512K | vt 512K  (~66MB total)
  unsigned short* wqb = (unsigned short*)(ws);
  unsigned short* wpb = (unsigned short*)(ws + 524288);
  unsigned short* xb  = (unsigned short*)(ws + 1048576);
  unsigned short* att = (unsigned short*)(ws + 1048576 + 33554432);
  unsigned short* kb  = (unsigned short*)(ws + 1048576 + 2ull * 33554432);
  unsigned short* vt  = (unsigned short*)(ws + 1048576 + 2ull * 33554432 + 524288);

  wconv<<<dim3(256), dim3(256), 0, stream>>>(Wq, Wp, wqb, wpb);
  xtrans<<<dim3(64, 8, 8), dim3(256), 0, stream>>>(x, xb);
  kvproj<<<dim3(4, 8, 8), dim3(256), 0, stream>>>(Ft, Wk, Wv, kb, vt);
  qattn<<<dim3(32, 4, 8), dim3(256), 0, stream>>>(wqb, xb, kb, vt, att);
  pproj<<<dim3(32, 4, 8), dim3(256), 0, stream>>>(wpb, att, x, bp, out);
}